// Round 7
// baseline (184.862 us; speedup 1.0000x reference)
//
#include <hip/hip_runtime.h>
#include <hip/hip_bf16.h>

#define IN_DIM 256
#define HC 128      // H*C = 4*32
#define HH 4
#define NEG_SLOPE 0.2f
#define EPB 1088    // edges per degree block (256*4 + 64)

typedef __attribute__((ext_vector_type(8))) short bf16x8;
typedef __attribute__((ext_vector_type(4))) float f32x4;

__device__ __forceinline__ unsigned short f2b(float f) {
    unsigned int u = __float_as_uint(f);
    u += 0x7FFFu + ((u >> 16) & 1u);          // RNE
    return (unsigned short)(u >> 16);
}
__device__ __forceinline__ float b2f(unsigned short u) {
    return __uint_as_float(((unsigned int)u) << 16);
}

// ---- prep: W -> Wt (bf16, [col][k]) ; block 0 -> graph1, block 1 -> graph2 ----
__global__ void prep_kernel(const float* __restrict__ W1, const float* __restrict__ W2,
                            unsigned short* __restrict__ Wt1, unsigned short* __restrict__ Wt2) {
    const float* W = blockIdx.x ? W2 : W1;
    unsigned short* Wt = blockIdx.x ? Wt2 : Wt1;
    for (int idx = threadIdx.x; idx < HC * IN_DIM; idx += 256) {
        int c = idx >> 8, k = idx & 255;
        Wt[idx] = f2b(W[k * HC + c]);
    }
}

// ---- gemm body: 256 threads = 4 waves, 16 rows/wave (64 rows/block) ----
__device__ __forceinline__ void gemm_body(int blk, int tid,
                                          const float* __restrict__ x,
                                          const unsigned short* __restrict__ Wt,
                                          const float* __restrict__ attS,
                                          const float* __restrict__ attD,
                                          unsigned short* __restrict__ hb,
                                          float* __restrict__ asrc,
                                          float* __restrict__ adst, int N) {
    const int lane = tid & 63;
    const int wid = tid >> 6;                 // 0..3
    const int lr = lane & 15, lg = lane >> 4;
    const int r0 = blk * 64 + wid * 16;
    int ra = r0 + lr; if (ra > N - 1) ra = N - 1;
    const float* A = x + (size_t)ra * IN_DIM + lg * 8;
    const unsigned short* B0 = Wt + (size_t)lr * IN_DIM + lg * 8;

    f32x4 acc[8];
#pragma unroll
    for (int t = 0; t < 8; ++t) acc[t] = (f32x4){0.f, 0.f, 0.f, 0.f};

#pragma unroll
    for (int k0 = 0; k0 < IN_DIM; k0 += 32) {
        float4 al = *(const float4*)(A + k0);
        float4 ah = *(const float4*)(A + k0 + 4);
        bf16x8 a;
        a[0] = f2b(al.x); a[1] = f2b(al.y); a[2] = f2b(al.z); a[3] = f2b(al.w);
        a[4] = f2b(ah.x); a[5] = f2b(ah.y); a[6] = f2b(ah.z); a[7] = f2b(ah.w);
#pragma unroll
        for (int t = 0; t < 8; ++t) {
            bf16x8 b = *(const bf16x8*)(B0 + t * 16 * IN_DIM + k0);
            acc[t] = __builtin_amdgcn_mfma_f32_16x16x32_bf16(a, b, acc[t], 0, 0, 0);
        }
    }

    float attS_r[8], attD_r[8];
#pragma unroll
    for (int t = 0; t < 8; ++t) {
        attS_r[t] = attS[t * 16 + lr];
        attD_r[t] = attD[t * 16 + lr];
    }

    // C layout: col = t*16 + (lane&15), row = r0 + 4*(lane>>4) + i
#pragma unroll
    for (int i = 0; i < 4; ++i) {
        int row = r0 + 4 * lg + i;
        float s[4] = {0.f, 0.f, 0.f, 0.f}, dd[4] = {0.f, 0.f, 0.f, 0.f};
#pragma unroll
        for (int t = 0; t < 8; ++t) {
            float c = acc[t][i];
            s[t >> 1] += c * attS_r[t];
            dd[t >> 1] += c * attD_r[t];
        }
#pragma unroll
        for (int m = 1; m < 16; m <<= 1) {
#pragma unroll
            for (int h = 0; h < 4; ++h) {
                s[h] += __shfl_xor(s[h], m);
                dd[h] += __shfl_xor(dd[h], m);
            }
        }
        if (row < N) {
#pragma unroll
            for (int t = 0; t < 8; ++t)
                hb[(size_t)row * HC + t * 16 + lr] = f2b(acc[t][i]);
            if (lr == 0) {
#pragma unroll
                for (int h = 0; h < 4; ++h) {
                    asrc[row * HH + h] = s[h];
                    adst[row * HH + h] = dd[h];
                }
            }
        }
    }
}

// ---- degree body: EPB edges per block ----
__device__ __forceinline__ void degree_body(int blk, int tid,
                                            const int* __restrict__ ei1, int E1, int S1,
                                            const int* __restrict__ ei2, int E2, int S2,
                                            int* __restrict__ deg1, int* __restrict__ deg2,
                                            int* __restrict__ rank) {
    const int base = blk * EPB + tid;
#pragma unroll
    for (int k = 0; k < 5; ++k) {
        if (k == 4 && tid >= 64) break;
        int i = base + k * 256;
        if (i < S1) {
            int dst = (i < E1) ? ei1[E1 + i] : i - E1;
            rank[i] = atomicAdd(&deg1[dst], 1);
        } else if (i < S1 + S2) {
            int q = i - S1;
            int dst = (q < E2) ? ei2[E2 + q] : q - E2;
            rank[i] = atomicAdd(&deg2[dst], 1);
        }
    }
}

// ---- MEGA1: even blocks gemm, odd blocks degree (interleaved residency) ----
__launch_bounds__(256)
__global__ void mega1_kernel(const float* __restrict__ x1,
                             const unsigned short* __restrict__ Wt1,
                             const float* __restrict__ attS1, const float* __restrict__ attD1,
                             unsigned short* __restrict__ hb1,
                             float* __restrict__ asrc1, float* __restrict__ adst1, int N1,
                             const float* __restrict__ x2,
                             const unsigned short* __restrict__ Wt2,
                             const float* __restrict__ attS2, const float* __restrict__ attD2,
                             unsigned short* __restrict__ hb2,
                             float* __restrict__ asrc2, float* __restrict__ adst2, int N2,
                             const int* __restrict__ ei1, int E1, int S1,
                             const int* __restrict__ ei2, int E2, int S2,
                             int* __restrict__ deg1, int* __restrict__ deg2,
                             int* __restrict__ rank,
                             int G1, int G2, int GD) {
    const int b = blockIdx.x;
    const int tid = threadIdx.x;
    if ((b & 1) == 0) {
        int g = b >> 1;
        if (g < G1) gemm_body(g, tid, x1, Wt1, attS1, attD1, hb1, asrc1, adst1, N1);
        else if (g < G1 + G2) gemm_body(g - G1, tid, x2, Wt2, attS2, attD2, hb2, asrc2, adst2, N2);
    } else {
        int d = b >> 1;
        if (d < GD) degree_body(d, tid, ei1, E1, S1, ei2, E2, S2, deg1, deg2, rank);
    }
}

__global__ void scan_block_kernel(const int* __restrict__ deg1, int* __restrict__ incl1,
                                  int* __restrict__ bsum1, int n1, int nb1,
                                  const int* __restrict__ deg2, int* __restrict__ incl2,
                                  int* __restrict__ bsum2, int n2) {
    const int* deg; int* incl; int* bsum; int n, bid;
    if ((int)blockIdx.x < nb1) { deg = deg1; incl = incl1; bsum = bsum1; n = n1; bid = blockIdx.x; }
    else { deg = deg2; incl = incl2; bsum = bsum2; n = n2; bid = blockIdx.x - nb1; }
    __shared__ int tmp[256];
    int t = threadIdx.x;
    int gid = bid * 256 + t;
    tmp[t] = (gid < n) ? deg[gid] : 0;
    __syncthreads();
    for (int off = 1; off < 256; off <<= 1) {
        int v = (t >= off) ? tmp[t - off] : 0;
        __syncthreads();
        tmp[t] += v;
        __syncthreads();
    }
    if (gid < n) incl[gid] = tmp[t];
    if (t == 255) bsum[bid] = tmp[255];
}

// fused top-scan (redundant per block, nb<=256) + excl = incl + off - deg
__global__ void finalize_scan_kernel(const int* __restrict__ incl1, const int* __restrict__ bsum1,
                                     const int* __restrict__ deg1, int* __restrict__ excl1,
                                     int n1, int nb1,
                                     const int* __restrict__ incl2, const int* __restrict__ bsum2,
                                     const int* __restrict__ deg2, int* __restrict__ excl2,
                                     int n2, int nb2) {
    const int *incl, *bsum, *deg; int* excl; int n, nb, bid;
    if ((int)blockIdx.x < nb1) { incl = incl1; bsum = bsum1; deg = deg1; excl = excl1; n = n1; nb = nb1; bid = blockIdx.x; }
    else { incl = incl2; bsum = bsum2; deg = deg2; excl = excl2; n = n2; nb = nb2; bid = blockIdx.x - nb1; }
    __shared__ int tmp[256];
    int t = threadIdx.x;
    tmp[t] = (t < nb) ? bsum[t] : 0;
    __syncthreads();
    for (int off = 1; off < 256; off <<= 1) {
        int v = (t >= off) ? tmp[t - off] : 0;
        __syncthreads();
        tmp[t] += v;
        __syncthreads();
    }
    int blockoff = (bid > 0) ? tmp[bid - 1] : 0;
    int i = bid * 256 + t;
    if (i < n) excl[i] = incl[i] + blockoff - deg[i];
}

// ---- scatter (atomic-free): record {src, pad, w_bf16[4]} at excl[dst]+rank ----
__global__ void scatter_kernel(const int* __restrict__ ei1, int E1, int S1,
                               const int* __restrict__ ei2, int E2, int S2,
                               const int* __restrict__ excl1, int4* __restrict__ esw1,
                               const int* __restrict__ excl2, int4* __restrict__ esw2,
                               const int* __restrict__ rank,
                               const float* __restrict__ as1, const float* __restrict__ ad1,
                               const float* __restrict__ as2, const float* __restrict__ ad2) {
    int i = blockIdx.x * 256 + threadIdx.x;
    int src, dst;
    const int* excl; int4* esw; const float *as, *ad;
    if (i < S1) {
        if (i < E1) { src = ei1[i]; dst = ei1[E1 + i]; } else { src = dst = i - E1; }
        excl = excl1; esw = esw1; as = as1; ad = ad1;
    } else if (i < S1 + S2) {
        int k = i - S1;
        if (k < E2) { src = ei2[k]; dst = ei2[E2 + k]; } else { src = dst = k - E2; }
        excl = excl2; esw = esw2; as = as2; ad = ad2;
    } else return;
    int pos = excl[dst] + rank[i];
    const float4 a = *(const float4*)(as + (size_t)src * HH);
    const float4 dv = *(const float4*)(ad + (size_t)dst * HH);
    float al[4] = {a.x + dv.x, a.y + dv.y, a.z + dv.z, a.w + dv.w};
    unsigned short wb[4];
#pragma unroll
    for (int h = 0; h < HH; ++h) {
        float v = al[h];
        v = v > 0.f ? v : NEG_SLOPE * v;
        wb[h] = f2b(__expf(v));      // no max-shift: |alpha| small, fp32-safe
    }
    int4 rec;
    rec.x = src;
    rec.y = 0;
    rec.z = (int)((unsigned)wb[0] | ((unsigned)wb[1] << 16));
    rec.w = (int)((unsigned)wb[2] | ((unsigned)wb[3] << 16));
    esw[pos] = rec;
}

// ---- gather: 32 lanes/node, 4-edge groups, depth-2 pipeline ----
__global__ void gather_kernel(const int* __restrict__ excl, const int* __restrict__ deg,
                              const int4* __restrict__ esw,
                              const unsigned short* __restrict__ hb,
                              const float* __restrict__ b,
                              const int* __restrict__ ga,       // nullable
                              const float* __restrict__ other,  // nullable
                              float* __restrict__ out, int N) {
    const int node = blockIdx.x * 8 + (threadIdx.x >> 5);
    if (node >= N) return;
    const int j = threadIdx.x & 31;
    const int head = j >> 3;
    const int d = deg[node];
    const int start = excl[node];
    const unsigned short* hbj = hb + 4 * j;

    float4 acc = {0.f, 0.f, 0.f, 0.f};
    float wsum = 0.f;

    int4 rC[4], rN[4];
    ushort4 hC[4];
#pragma unroll
    for (int k = 0; k < 4; ++k) rC[k] = esw[start + k];
#pragma unroll
    for (int k = 0; k < 4; ++k)
        hC[k] = *(const ushort4*)(hbj + (size_t)rC[k].x * HC);
#pragma unroll
    for (int k = 0; k < 4; ++k) rN[k] = esw[start + 4 + k];

    for (int e = 0; e < d; e += 4) {
#pragma unroll
        for (int k = 0; k < 4; ++k) {
            unsigned int pk = (head < 2) ? (unsigned)rC[k].z : (unsigned)rC[k].w;
            unsigned short wu = (head & 1) ? (unsigned short)(pk >> 16)
                                           : (unsigned short)(pk & 0xffff);
            float w = (e + k < d) ? b2f(wu) : 0.f;
            acc.x += w * b2f(hC[k].x);
            acc.y += w * b2f(hC[k].y);
            acc.z += w * b2f(hC[k].z);
            acc.w += w * b2f(hC[k].w);
            wsum += w;
        }
#pragma unroll
        for (int k = 0; k < 4; ++k) rC[k] = rN[k];
#pragma unroll
        for (int k = 0; k < 4; ++k)
            hC[k] = *(const ushort4*)(hbj + (size_t)rC[k].x * HC);
#pragma unroll
        for (int k = 0; k < 4; ++k) rN[k] = esw[start + e + 8 + k];
    }

    const float inv = 1.f / wsum;
    const float4 bb = *(const float4*)(b + 4 * j);
    float4 o = {acc.x * inv + bb.x, acc.y * inv + bb.y,
                acc.z * inv + bb.z, acc.w * inv + bb.w};
    if (ga) {
        const float4 ov = *(const float4*)(other + (size_t)ga[node] * HC + 4 * j);
        o.x += ov.x; o.y += ov.y; o.z += ov.z; o.w += ov.w;
    }
    *(float4*)(out + (size_t)node * HC + 4 * j) = o;
}

extern "C" void kernel_launch(void* const* d_in, const int* in_sizes, int n_in,
                              void* d_out, int out_size, void* d_ws, size_t ws_size,
                              hipStream_t stream) {
    const float* x1  = (const float*)d_in[0];
    const int*   ei1 = (const int*)d_in[1];
    const float* x2  = (const float*)d_in[2];
    const int*   ei2 = (const int*)d_in[3];
    const int*   ga  = (const int*)d_in[4];
    const float* W1    = (const float*)d_in[5];
    const float* attS1 = (const float*)d_in[6];
    const float* attD1 = (const float*)d_in[7];
    const float* b1    = (const float*)d_in[8];
    const float* W2    = (const float*)d_in[9];
    const float* attS2 = (const float*)d_in[10];
    const float* attD2 = (const float*)d_in[11];
    const float* b2    = (const float*)d_in[12];

    const int N1 = in_sizes[0] / IN_DIM;
    const int E1 = in_sizes[1] / 2;
    const int N2 = in_sizes[2] / IN_DIM;
    const int E2 = in_sizes[3] / 2;
    const int S1 = E1 + N1, S2 = E2 + N2;

    // ---- workspace layout ----
    char* p = (char*)d_ws;
    auto alloc = [&](size_t bytes) {
        char* r = p; p += (bytes + 511) & ~(size_t)511; return r;
    };
    unsigned short* hb1 = (unsigned short*)alloc((size_t)N1 * HC * 2);
    unsigned short* hb2 = (unsigned short*)alloc((size_t)N2 * HC * 2);
    unsigned short* Wt1 = (unsigned short*)alloc((size_t)IN_DIM * HC * 2);
    unsigned short* Wt2 = (unsigned short*)alloc((size_t)IN_DIM * HC * 2);
    float* asrc1 = (float*)alloc((size_t)N1 * HH * 4);
    float* adst1 = (float*)alloc((size_t)N1 * HH * 4);
    float* asrc2 = (float*)alloc((size_t)N2 * HH * 4);
    float* adst2 = (float*)alloc((size_t)N2 * HH * 4);
    int* deg1 = (int*)alloc((size_t)(N1 + N2) * 4);   // deg1|deg2 -> one memset
    int* deg2 = deg1 + N1;
    int* incl1 = (int*)alloc((size_t)N1 * 4);
    int* incl2 = (int*)alloc((size_t)N2 * 4);
    int* excl1 = (int*)alloc((size_t)N1 * 4);
    int* excl2 = (int*)alloc((size_t)N2 * 4);
    int* bsum1 = (int*)alloc(256 * 4);
    int* bsum2 = (int*)alloc(256 * 4);
    int* rank  = (int*)alloc((size_t)(S1 + S2) * 4);
    int4* esw1 = (int4*)alloc((size_t)(S1 + 16) * 16);
    int4* esw2 = (int4*)alloc((size_t)(S2 + 16) * 16);

    float* out1 = (float*)d_out;
    float* out2 = (float*)d_out + (size_t)N1 * HC;

    hipMemsetAsync(deg1, 0, (size_t)(N1 + N2) * 4, stream);
    hipMemsetAsync(esw1 + S1, 0, 16 * 16, stream);   // zero prefetch pad
    hipMemsetAsync(esw2 + S2, 0, 16 * 16, stream);

    prep_kernel<<<2, 256, 0, stream>>>(W1, W2, Wt1, Wt2);

    // MEGA1: gemm1|gemm2 on even blocks, degree_rank on odd blocks.
    // Interleaved blockIdx -> resident mix is ~50/50 from t=0, so the
    // memory-side atomic unit and the MFMA/HBM-read pipes overlap for real.
    const int G1 = (N1 + 63) / 64, G2 = (N2 + 63) / 64;   // 782, 157
    const int GD = (S1 + S2 + EPB - 1) / EPB;             // 938
    const int G = G1 + G2;                                // 939
    const int T = 2 * (G > GD ? G : GD);
    mega1_kernel<<<T, 256, 0, stream>>>(
        x1, Wt1, attS1, attD1, hb1, asrc1, adst1, N1,
        x2, Wt2, attS2, attD2, hb2, asrc2, adst2, N2,
        ei1, E1, S1, ei2, E2, S2, deg1, deg2, rank, G1, G2, GD);

    const int nb1 = (N1 + 255) / 256, nb2 = (N2 + 255) / 256;  // 196, 40
    scan_block_kernel<<<nb1 + nb2, 256, 0, stream>>>(deg1, incl1, bsum1, N1, nb1,
                                                     deg2, incl2, bsum2, N2);
    finalize_scan_kernel<<<nb1 + nb2, 256, 0, stream>>>(incl1, bsum1, deg1, excl1, N1, nb1,
                                                        incl2, bsum2, deg2, excl2, N2, nb2);

    scatter_kernel<<<(S1 + S2 + 255) / 256, 256, 0, stream>>>(
        ei1, E1, S1, ei2, E2, S2, excl1, esw1, excl2, esw2, rank,
        asrc1, adst1, asrc2, adst2);

    // gather: graph2 first (graph1 reads out2 through ga)
    gather_kernel<<<(N2 + 7) / 8, 256, 0, stream>>>(excl2, deg2, esw2, hb2,
                                                    b2, nullptr, nullptr, out2, N2);
    gather_kernel<<<(N1 + 7) / 8, 256, 0, stream>>>(excl1, deg1, esw1, hb1,
                                                    b1, ga, out2, out1, N1);
}